// Round 5
// baseline (6137.861 us; speedup 1.0000x reference)
//
#include <hip/hip_runtime.h>

#define HID 512
#define NB  256
#define TT  256
#define DIN 64
#define BATCH_G 128      // batch rows per group
#define JB_PER_G 128     // j-blocks per group
#define HBUF 131072      // shorts per h buffer: [16 bt][16 jt][64][8]

typedef __attribute__((ext_vector_type(8))) short short8;
typedef __attribute__((ext_vector_type(4))) float f32x4;

__device__ __forceinline__ unsigned short f2bf(float f) {
    unsigned int u = __float_as_uint(f);
    u += 0x7FFF + ((u >> 16) & 1);
    return (unsigned short)(u >> 16);
}
__device__ __forceinline__ float bf2f(unsigned short h) {
    return __uint_as_float(((unsigned int)h) << 16);
}

#define MFMA3(acc, ah, al, bh, bl)                                          \
    acc = __builtin_amdgcn_mfma_f32_16x16x32_bf16(ah, bh, acc, 0, 0, 0);    \
    acc = __builtin_amdgcn_mfma_f32_16x16x32_bf16(ah, bl, acc, 0, 0, 0);    \
    acc = __builtin_amdgcn_mfma_f32_16x16x32_bf16(al, bh, acc, 0, 0, 0);

// LDS layout (shorts): sW0 h/l: 18*512 each; sW1 h/l: 32*512 each; then sG floats
#define SW0_N 9216
#define SW1_N 16384
#define LDS_BYTES ((SW0_N * 2 + SW1_N * 2) * 2 + 128 * 17 * 4)

// ---- legacy barrier (fallback path): acquire/release with fences ----
__device__ __forceinline__ void group_barrier_fenced(int* gflags, int it, int jb) {
    __syncthreads();
    int* slice = gflags + it * JB_PER_G;
    if (threadIdx.x == 0)
        __hip_atomic_store(slice + jb, 1, __ATOMIC_RELEASE, __HIP_MEMORY_SCOPE_AGENT);
    if (threadIdx.x < JB_PER_G) {
        int* p = slice + threadIdx.x;
        int polls = 0;
        while (__hip_atomic_load(p, __ATOMIC_RELAXED, __HIP_MEMORY_SCOPE_AGENT) == 0) {
            __builtin_amdgcn_s_sleep(1);
            if ((++polls & 255) == 0)
                (void)__hip_atomic_load(p, __ATOMIC_ACQUIRE, __HIP_MEMORY_SCOPE_AGENT);
        }
    }
    __syncthreads();
    if (threadIdx.x == 0)
        (void)__hip_atomic_load(slice, __ATOMIC_ACQUIRE, __HIP_MEMORY_SCOPE_AGENT);
    __syncthreads();
}

// ---- fence-free barrier (per-t buffers): vmcnt drain + relaxed flags only ----
__device__ __forceinline__ void group_barrier_pert(int* gflags, int it, int jb) {
    asm volatile("s_waitcnt vmcnt(0)" ::: "memory");   // every wave drains its h stores to LLC
    __syncthreads();
    int* slice = gflags + it * JB_PER_G;
    if (threadIdx.x == 0)
        __hip_atomic_store(slice + jb, 1, __ATOMIC_RELAXED, __HIP_MEMORY_SCOPE_AGENT);
    if (threadIdx.x < JB_PER_G) {
        int* p = slice + threadIdx.x;
        int polls = 0;
        while (__hip_atomic_load(p, __ATOMIC_RELAXED, __HIP_MEMORY_SCOPE_AGENT) == 0) {
            __builtin_amdgcn_s_sleep(1);
            if ((++polls & 1023) == 0)   // hang-insurance only; rare
                (void)__hip_atomic_load(p, __ATOMIC_ACQUIRE, __HIP_MEMORY_SCOPE_AGENT);
        }
    }
    __syncthreads();
}

// packed 2-lane h store: lanes (l, l+1) hold adjacent shorts; even lane stores u32
__device__ __forceinline__ void store_h_pair(unsigned short* buf, size_t hoff,
                                             unsigned short v, int l) {
    unsigned int hv = (unsigned int)v;
    unsigned int up = __shfl_down(hv, 1);
    if ((l & 1) == 0)
        __hip_atomic_store((unsigned int*)(buf + hoff), hv | (up << 16),
                           __ATOMIC_RELAXED, __HIP_MEMORY_SCOPE_AGENT);
}

template<bool PERT>
__global__ __launch_bounds__(512, 2) void lstm_persistent(
    const float* __restrict__ x,
    const float* __restrict__ Wih0, const float* __restrict__ Whh0,
    const float* __restrict__ bih0, const float* __restrict__ bhh0,
    const float* __restrict__ Wih1, const float* __restrict__ Whh1,
    const float* __restrict__ bih1, const float* __restrict__ bhh1,
    const float* __restrict__ headw, const float* __restrict__ headb,
    unsigned short* ws, unsigned short* h0base, unsigned short* h1base,
    int* flags, float* __restrict__ out)
{
    extern __shared__ unsigned short lds[];
    unsigned short* sW0h = lds;
    unsigned short* sW0l = sW0h + SW0_N;
    unsigned short* sW1h = sW0l + SW0_N;
    unsigned short* sW1l = sW1h + SW1_N;
    float* sG = (float*)(sW1l + SW1_N);          // [128][17]

    const int tid = threadIdx.x;
    const int l   = tid & 63;
    const int w   = tid >> 6;         // wave 0..7
    const int bid = blockIdx.x;
    const int g   = bid & 1;          // batch group
    const int jb  = bid >> 1;         // j-block 0..127 (hidden units jb*4..jb*4+3)

    int* gflags = flags + g * (TT + 1) * JB_PER_G;

    // ---------------- weight preload: fp32 -> hi/lo bf16 fragments in LDS ----------------
    const int r  = l & 15;                       // gate-row within tile
    const int ks = (l >> 4) * 8;                 // k-sub offset within 32-chunk
    const int n  = (r >> 2) * HID + jb * 4 + (r & 3);   // weight row index

    {
        for (int kt = w; kt < 18; kt += 8) {
            const float* src = (kt < 2) ? (Wih0 + (size_t)n * DIN + kt * 32 + ks)
                                        : (Whh0 + (size_t)n * HID + (kt - 2) * 32 + ks);
            float v[8];
            *(float4*)&v[0] = *(const float4*)src;
            *(float4*)&v[4] = *(const float4*)(src + 4);
            union { unsigned short u[8]; uint4 q; } ph, pl;
            #pragma unroll
            for (int e = 0; e < 8; ++e) {
                unsigned short h = f2bf(v[e]);
                ph.u[e] = h; pl.u[e] = f2bf(v[e] - bf2f(h));
            }
            *(uint4*)&sW0h[(kt * 64 + l) * 8] = ph.q;
            *(uint4*)&sW0l[(kt * 64 + l) * 8] = pl.q;
        }
        for (int kt = w; kt < 32; kt += 8) {
            const float* src = (kt < 16) ? (Wih1 + (size_t)n * HID + kt * 32 + ks)
                                         : (Whh1 + (size_t)n * HID + (kt - 16) * 32 + ks);
            float v[8];
            *(float4*)&v[0] = *(const float4*)src;
            *(float4*)&v[4] = *(const float4*)(src + 4);
            union { unsigned short u[8]; uint4 q; } ph, pl;
            #pragma unroll
            for (int e = 0; e < 8; ++e) {
                unsigned short h = f2bf(v[e]);
                ph.u[e] = h; pl.u[e] = f2bf(v[e] - bf2f(h));
            }
            *(uint4*)&sW1h[(kt * 64 + l) * 8] = ph.q;
            *(uint4*)&sW1l[(kt * 64 + l) * 8] = pl.q;
        }
    }

    float bias0[4], bias1[4];
    #pragma unroll
    for (int gi = 0; gi < 4; ++gi) {
        const int nn = gi * HID + jb * 4 + (l & 3);
        bias0[gi] = bih0[nn] + bhh0[nn];
        bias1[gi] = bih1[nn] + bhh1[nn];
    }
    float c0 = 0.f, c1 = 0.f;

    const int jj      = l & 3;
    const int b_local = 16 * w + (l >> 2);
    const int b_glob  = g * BATCH_G + b_local;
    const int j_glob  = jb * 4 + jj;
    const size_t hoff = ((((size_t)(b_glob >> 4)) * 16 + (j_glob >> 5)) * 64
                         + ((b_glob & 15) | (((j_glob >> 3) & 3) << 4))) * 8 + (j_glob & 7);

    const int bt = g * 8 + w;        // this wave's global batch tile

    __syncthreads();                 // weights ready

    int cur0 = 0, cur1 = 0;
    for (int it = 0; it <= TT; ++it) {
        const unsigned short *h0c_h, *h0c_l, *h1c_h, *h1c_l;
        unsigned short *h0n_h, *h0n_l, *h1n_h, *h1n_l;
        if constexpr (PERT) {
            h0c_h = h0base + (size_t)it * (2 * HBUF);            h0c_l = h0c_h + HBUF;
            h0n_h = h0base + (size_t)(it + 1) * (2 * HBUF);      h0n_l = h0n_h + HBUF;
            h1c_h = h1base + (size_t)(it > 0 ? it - 1 : 0) * (2 * HBUF); h1c_l = h1c_h + HBUF;
            h1n_h = h1base + (size_t)it * (2 * HBUF);            h1n_l = h1n_h + HBUF;
        } else {
            h0c_h = ws + (size_t)(cur0 * 2) * HBUF;              h0c_l = h0c_h + HBUF;
            h0n_h = ws + (size_t)((cur0 ^ 1) * 2) * HBUF;        h0n_l = h0n_h + HBUF;
            h1c_h = ws + (size_t)(4 + cur1 * 2) * HBUF;          h1c_l = h1c_h + HBUF;
            h1n_h = ws + (size_t)(4 + (cur1 ^ 1) * 2) * HBUF;    h1n_l = h1n_h + HBUF;
        }

        // ================= layer 0, t = it =================
        if (it < TT) {
            f32x4 acc[2] = {{0.f,0.f,0.f,0.f},{0.f,0.f,0.f,0.f}};
            #pragma unroll
            for (int kt = 0; kt < 2; ++kt) {
                const int brow = g * BATCH_G + w * 16 + (l & 15);
                const float* src = x + ((size_t)brow * TT + it) * DIN + kt * 32 + ks;
                float v[8];
                *(float4*)&v[0] = *(const float4*)src;
                *(float4*)&v[4] = *(const float4*)(src + 4);
                union { unsigned short u[8]; short8 s; } ah, al;
                #pragma unroll
                for (int e = 0; e < 8; ++e) {
                    unsigned short h = f2bf(v[e]);
                    ah.u[e] = h; al.u[e] = f2bf(v[e] - bf2f(h));
                }
                short8 bh = *(const short8*)&sW0h[(kt * 64 + l) * 8];
                short8 bl = *(const short8*)&sW0l[(kt * 64 + l) * 8];
                MFMA3(acc[kt & 1], ah.s, al.s, bh, bl);
            }
            #pragma unroll
            for (int kt = 0; kt < 16; ++kt) {
                const size_t o = (((size_t)bt * 16 + kt) * 64 + l) * 8;
                short8 ah = *(const short8*)&h0c_h[o];
                short8 al = *(const short8*)&h0c_l[o];
                short8 bh = *(const short8*)&sW0h[((kt + 2) * 64 + l) * 8];
                short8 bl = *(const short8*)&sW0l[((kt + 2) * 64 + l) * 8];
                MFMA3(acc[kt & 1], ah, al, bh, bl);
            }
            #pragma unroll
            for (int q = 0; q < 4; ++q)
                sG[(16 * w + (l >> 4) * 4 + q) * 17 + (l & 15)] = acc[0][q] + acc[1][q];
            __syncthreads();
            {
                const int br = 16 * w + (l >> 2);
                const float gi_ = sG[br * 17 + jj]      + bias0[0];
                const float gf_ = sG[br * 17 + 4 + jj]  + bias0[1];
                const float gg_ = sG[br * 17 + 8 + jj]  + bias0[2];
                const float go_ = sG[br * 17 + 12 + jj] + bias0[3];
                const float iG = 1.f / (1.f + expf(-gi_));
                const float fG = 1.f / (1.f + expf(-gf_));
                const float gT = tanhf(gg_);
                const float oG = 1.f / (1.f + expf(-go_));
                c0 = fmaf(fG, c0, iG * gT);
                const float h = oG * tanhf(c0);
                const unsigned short hh = f2bf(h);
                const unsigned short hl = f2bf(h - bf2f(hh));
                if constexpr (PERT) {
                    store_h_pair(h0n_h, hoff, hh, l);
                    store_h_pair(h0n_l, hoff, hl, l);
                } else {
                    h0n_h[hoff] = hh;
                    h0n_l[hoff] = hl;
                }
            }
            __syncthreads();
        }

        // ================= layer 1, t = it-1 =================
        if (it > 0) {
            f32x4 acc[2] = {{0.f,0.f,0.f,0.f},{0.f,0.f,0.f,0.f}};
            #pragma unroll
            for (int kt = 0; kt < 16; ++kt) {
                const size_t o = (((size_t)bt * 16 + kt) * 64 + l) * 8;
                short8 ah = *(const short8*)&h0c_h[o];
                short8 al = *(const short8*)&h0c_l[o];
                short8 bh = *(const short8*)&sW1h[(kt * 64 + l) * 8];
                short8 bl = *(const short8*)&sW1l[(kt * 64 + l) * 8];
                MFMA3(acc[kt & 1], ah, al, bh, bl);
            }
            #pragma unroll
            for (int kt = 0; kt < 16; ++kt) {
                const size_t o = (((size_t)bt * 16 + kt) * 64 + l) * 8;
                short8 ah = *(const short8*)&h1c_h[o];
                short8 al = *(const short8*)&h1c_l[o];
                short8 bh = *(const short8*)&sW1h[((kt + 16) * 64 + l) * 8];
                short8 bl = *(const short8*)&sW1l[((kt + 16) * 64 + l) * 8];
                MFMA3(acc[kt & 1], ah, al, bh, bl);
            }
            #pragma unroll
            for (int q = 0; q < 4; ++q)
                sG[(16 * w + (l >> 4) * 4 + q) * 17 + (l & 15)] = acc[0][q] + acc[1][q];
            __syncthreads();
            {
                const int br = 16 * w + (l >> 2);
                const float gi_ = sG[br * 17 + jj]      + bias1[0];
                const float gf_ = sG[br * 17 + 4 + jj]  + bias1[1];
                const float gg_ = sG[br * 17 + 8 + jj]  + bias1[2];
                const float go_ = sG[br * 17 + 12 + jj] + bias1[3];
                const float iG = 1.f / (1.f + expf(-gi_));
                const float fG = 1.f / (1.f + expf(-gf_));
                const float gT = tanhf(gg_);
                const float oG = 1.f / (1.f + expf(-go_));
                c1 = fmaf(fG, c1, iG * gT);
                const float h = oG * tanhf(c1);
                const unsigned short hh = f2bf(h);
                const unsigned short hl = f2bf(h - bf2f(hh));
                if constexpr (PERT) {
                    store_h_pair(h1n_h, hoff, hh, l);
                    store_h_pair(h1n_l, hoff, hl, l);
                } else {
                    h1n_h[hoff] = hh;
                    h1n_l[hoff] = hl;
                }
            }
            __syncthreads();
        }

        if constexpr (PERT) group_barrier_pert(gflags, it, jb);
        else                group_barrier_fenced(gflags, it, jb);
        cur0 ^= 1; cur1 ^= 1;
    }

    // ================= head: out[b] = h1_last . w + b =================
    if (jb == 0) {
        const unsigned short* h1h = PERT ? (h1base + (size_t)TT * (2 * HBUF))
                                         : (ws + (size_t)(4 + cur1 * 2) * HBUF);
        const unsigned short* h1l = h1h + HBUF;
        const int bl_ = tid >> 2;
        const int qd  = tid & 3;
        const int b   = g * BATCH_G + bl_;
        const int btw = b >> 4;
        float s = 0.f;
        #pragma unroll
        for (int jt = qd * 4; jt < qd * 4 + 4; ++jt) {
            #pragma unroll
            for (int q2 = 0; q2 < 4; ++q2) {
                const size_t off = (((size_t)btw * 16 + jt) * 64 + ((b & 15) | (q2 << 4))) * 8;
                short8 vh = *(const short8*)&h1h[off];
                short8 vl = *(const short8*)&h1l[off];
                const int j0 = jt * 32 + q2 * 8;
                #pragma unroll
                for (int e = 0; e < 8; ++e)
                    s += (bf2f((unsigned short)vh[e]) + bf2f((unsigned short)vl[e])) * headw[j0 + e];
            }
        }
        s += __shfl_down(s, 2, 4);
        s += __shfl_down(s, 1, 4);
        if (qd == 0) out[b] = s + headb[0];
    }
}

extern "C" void kernel_launch(void* const* d_in, const int* in_sizes, int n_in,
                              void* d_out, int out_size, void* d_ws, size_t ws_size,
                              hipStream_t stream) {
    const float* x      = (const float*)d_in[0];
    const float* W_ih0  = (const float*)d_in[1];
    const float* W_hh0  = (const float*)d_in[2];
    const float* b_ih0  = (const float*)d_in[3];
    const float* b_hh0  = (const float*)d_in[4];
    const float* W_ih1  = (const float*)d_in[5];
    const float* W_hh1  = (const float*)d_in[6];
    const float* b_ih1  = (const float*)d_in[7];
    const float* b_hh1  = (const float*)d_in[8];
    const float* head_w = (const float*)d_in[9];
    const float* head_b = (const float*)d_in[10];
    float* out = (float*)d_out;
    unsigned short* ws16 = (unsigned short*)d_ws;

    // ---- per-t layout: [flags (263 KB)][pad to 1MB][h0: 257 x 512KB][h1: 257 x 512KB]
    const size_t HB_AL       = 1 << 20;
    const size_t BUF_BYTES   = (size_t)2 * HBUF * 2;                 // 512 KB per (layer,t)
    const size_t CHAIN_BYTES = (size_t)(TT + 1) * BUF_BYTES;
    const size_t NEED        = HB_AL + 2 * CHAIN_BYTES + BUF_BYTES;  // + slack

    if (ws_size >= NEED) {
        int* flags = (int*)d_ws;
        unsigned short* h0base = (unsigned short*)((char*)d_ws + HB_AL);
        unsigned short* h1base = (unsigned short*)((char*)d_ws + HB_AL + CHAIN_BYTES);
        // zero flags + h0[0] (contiguous from 0) and h1[0]
        hipMemsetAsync(d_ws, 0, HB_AL + BUF_BYTES, stream);
        hipMemsetAsync((void*)h1base, 0, BUF_BYTES, stream);
        hipFuncSetAttribute((const void*)lstm_persistent<true>,
                            hipFuncAttributeMaxDynamicSharedMemorySize, LDS_BYTES);
        lstm_persistent<true><<<dim3(256), dim3(512), LDS_BYTES, stream>>>(
            x, W_ih0, W_hh0, b_ih0, b_hh0, W_ih1, W_hh1, b_ih1, b_hh1,
            head_w, head_b, ws16, h0base, h1base, flags, out);
    } else {
        // fallback: round-4 ping-pong layout
        int* flags = (int*)(ws16 + (size_t)8 * HBUF);
        const size_t zero_bytes = (size_t)8 * HBUF * 2 + (size_t)2 * (TT + 1) * JB_PER_G * 4;
        hipMemsetAsync(d_ws, 0, zero_bytes, stream);
        hipFuncSetAttribute((const void*)lstm_persistent<false>,
                            hipFuncAttributeMaxDynamicSharedMemorySize, LDS_BYTES);
        lstm_persistent<false><<<dim3(256), dim3(512), LDS_BYTES, stream>>>(
            x, W_ih0, W_hh0, b_ih0, b_hh0, W_ih1, W_hh1, b_ih1, b_hh1,
            head_w, head_b, ws16, nullptr, nullptr, flags, out);
    }
}

// Round 6
// 4463.498 us; speedup vs baseline: 1.3751x; 1.3751x over previous
//
#include <hip/hip_runtime.h>

#define HID 512
#define NB  256
#define TT  256
#define DIN 64
#define BATCH_G 128      // batch rows per group
#define JB_PER_G 128     // j-blocks per group
#define HBUF 131072      // shorts per h buffer: [16 bt][16 jt][64][8]

typedef __attribute__((ext_vector_type(8))) short short8;
typedef __attribute__((ext_vector_type(4))) float f32x4;

__device__ __forceinline__ unsigned short f2bf(float f) {
    unsigned int u = __float_as_uint(f);
    u += 0x7FFF + ((u >> 16) & 1);
    return (unsigned short)(u >> 16);
}
__device__ __forceinline__ float bf2f(unsigned short h) {
    return __uint_as_float(((unsigned int)h) << 16);
}

// ---- LLC-coherent (cross-XCD) 4B access, explicit sc0/sc1 cache bits ----
__device__ __forceinline__ void st_u32_llc(unsigned int* p, unsigned int v) {
    asm volatile("global_store_dword %0, %1, off sc0 sc1" :: "v"(p), "v"(v) : "memory");
}
__device__ __forceinline__ unsigned int ld_u32_llc(const unsigned int* p) {
    unsigned int v;
    asm volatile("global_load_dword %0, %1, off sc0 sc1\n\ts_waitcnt vmcnt(0)"
                 : "=v"(v) : "v"(p) : "memory");
    return v;
}

#define MFMA3(acc, ah, al, bh, bl)                                          \
    acc = __builtin_amdgcn_mfma_f32_16x16x32_bf16(ah, bh, acc, 0, 0, 0);    \
    acc = __builtin_amdgcn_mfma_f32_16x16x32_bf16(ah, bl, acc, 0, 0, 0);    \
    acc = __builtin_amdgcn_mfma_f32_16x16x32_bf16(al, bh, acc, 0, 0, 0);

// LDS layout (shorts): sW0 h/l: 18*512 each; sW1 h/l: 32*512 each; then sG floats
#define SW0_N 9216
#define SW1_N 16384
#define LDS_BYTES ((SW0_N * 2 + SW1_N * 2) * 2 + 128 * 17 * 4)

// ---- barrier: vmcnt drain -> LLC flag store -> LLC polling (no invalidations)
// ---- -> ONE agent-acquire fence per block (invalidate stale L1/L2 once)
__device__ __forceinline__ void group_barrier(int* gflags, int it, int jb) {
    asm volatile("s_waitcnt vmcnt(0)" ::: "memory");  // h stores complete at LLC
    __syncthreads();
    unsigned int* slice = (unsigned int*)(gflags + it * JB_PER_G);
    if (threadIdx.x == 0) st_u32_llc(slice + jb, 1u);
    if (threadIdx.x < JB_PER_G) {
        unsigned int* p = slice + threadIdx.x;
        while (ld_u32_llc(p) == 0u) __builtin_amdgcn_s_sleep(2);
    }
    __syncthreads();
    if (threadIdx.x < 64)  // one wave: invalidate this CU's L1 + XCD L2 once
        __builtin_amdgcn_fence(__ATOMIC_ACQUIRE, "agent");
    __syncthreads();
}

// packed 2-lane h store: lanes (l, l+1) hold adjacent shorts; even lane stores u32
__device__ __forceinline__ void store_h_pair(unsigned short* buf, size_t hoff,
                                             unsigned short v, int l) {
    unsigned int hv = (unsigned int)v;
    unsigned int up = __shfl_down(hv, 1);
    if ((l & 1) == 0)
        st_u32_llc((unsigned int*)(buf + hoff), hv | (up << 16));
}

__global__ __launch_bounds__(512, 2) void lstm_persistent(
    const float* __restrict__ x,
    const float* __restrict__ Wih0, const float* __restrict__ Whh0,
    const float* __restrict__ bih0, const float* __restrict__ bhh0,
    const float* __restrict__ Wih1, const float* __restrict__ Whh1,
    const float* __restrict__ bih1, const float* __restrict__ bhh1,
    const float* __restrict__ headw, const float* __restrict__ headb,
    unsigned short* ws, int* flags, float* __restrict__ out)
{
    extern __shared__ unsigned short lds[];
    unsigned short* sW0h = lds;
    unsigned short* sW0l = sW0h + SW0_N;
    unsigned short* sW1h = sW0l + SW0_N;
    unsigned short* sW1l = sW1h + SW1_N;
    float* sG = (float*)(sW1l + SW1_N);          // [128][17]

    const int tid = threadIdx.x;
    const int l   = tid & 63;
    const int w   = tid >> 6;         // wave 0..7
    const int bid = blockIdx.x;
    const int g   = bid & 1;          // batch group
    const int jb  = bid >> 1;         // j-block 0..127 (hidden units jb*4..jb*4+3)

    int* gflags = flags + g * (TT + 1) * JB_PER_G;

    // ---------------- weight preload: fp32 -> hi/lo bf16 fragments in LDS ----------------
    const int r  = l & 15;                       // gate-row within tile
    const int ks = (l >> 4) * 8;                 // k-sub offset within 32-chunk
    const int n  = (r >> 2) * HID + jb * 4 + (r & 3);   // weight row index

    {
        for (int kt = w; kt < 18; kt += 8) {
            const float* src = (kt < 2) ? (Wih0 + (size_t)n * DIN + kt * 32 + ks)
                                        : (Whh0 + (size_t)n * HID + (kt - 2) * 32 + ks);
            float v[8];
            *(float4*)&v[0] = *(const float4*)src;
            *(float4*)&v[4] = *(const float4*)(src + 4);
            union { unsigned short u[8]; uint4 q; } ph, pl;
            #pragma unroll
            for (int e = 0; e < 8; ++e) {
                unsigned short h = f2bf(v[e]);
                ph.u[e] = h; pl.u[e] = f2bf(v[e] - bf2f(h));
            }
            *(uint4*)&sW0h[(kt * 64 + l) * 8] = ph.q;
            *(uint4*)&sW0l[(kt * 64 + l) * 8] = pl.q;
        }
        for (int kt = w; kt < 32; kt += 8) {
            const float* src = (kt < 16) ? (Wih1 + (size_t)n * HID + kt * 32 + ks)
                                         : (Whh1 + (size_t)n * HID + (kt - 16) * 32 + ks);
            float v[8];
            *(float4*)&v[0] = *(const float4*)src;
            *(float4*)&v[4] = *(const float4*)(src + 4);
            union { unsigned short u[8]; uint4 q; } ph, pl;
            #pragma unroll
            for (int e = 0; e < 8; ++e) {
                unsigned short h = f2bf(v[e]);
                ph.u[e] = h; pl.u[e] = f2bf(v[e] - bf2f(h));
            }
            *(uint4*)&sW1h[(kt * 64 + l) * 8] = ph.q;
            *(uint4*)&sW1l[(kt * 64 + l) * 8] = pl.q;
        }
    }

    float bias0[4], bias1[4];
    #pragma unroll
    for (int gi = 0; gi < 4; ++gi) {
        const int nn = gi * HID + jb * 4 + (l & 3);
        bias0[gi] = bih0[nn] + bhh0[nn];
        bias1[gi] = bih1[nn] + bhh1[nn];
    }
    float c0 = 0.f, c1 = 0.f;

    const int jj      = l & 3;
    const int b_local = 16 * w + (l >> 2);
    const int b_glob  = g * BATCH_G + b_local;
    const int j_glob  = jb * 4 + jj;
    const size_t hoff = ((((size_t)(b_glob >> 4)) * 16 + (j_glob >> 5)) * 64
                         + ((b_glob & 15) | (((j_glob >> 3) & 3) << 4))) * 8 + (j_glob & 7);

    const int bt = g * 8 + w;        // this wave's global batch tile

    // x prefetch registers (fp32, converted at use)
    const int xrow = g * BATCH_G + w * 16 + (l & 15);
    float xv0[8], xv1[8];
    {
        const float* s0 = x + ((size_t)xrow * TT + 0) * DIN + ks;
        *(float4*)&xv0[0] = *(const float4*)s0;
        *(float4*)&xv0[4] = *(const float4*)(s0 + 4);
        *(float4*)&xv1[0] = *(const float4*)(s0 + 32);
        *(float4*)&xv1[4] = *(const float4*)(s0 + 36);
    }

    __syncthreads();                 // weights ready

    int cur0 = 0, cur1 = 0;
    for (int it = 0; it <= TT; ++it) {
        const unsigned short* h0c_h = ws + (size_t)(cur0 * 2) * HBUF;
        const unsigned short* h0c_l = h0c_h + HBUF;
        unsigned short* h0n_h = ws + (size_t)((cur0 ^ 1) * 2) * HBUF;
        unsigned short* h0n_l = h0n_h + HBUF;
        const unsigned short* h1c_h = ws + (size_t)(4 + cur1 * 2) * HBUF;
        const unsigned short* h1c_l = h1c_h + HBUF;
        unsigned short* h1n_h = ws + (size_t)(4 + (cur1 ^ 1) * 2) * HBUF;
        unsigned short* h1n_l = h1n_h + HBUF;

        // ================= layer 0, t = it =================
        if (it < TT) {
            f32x4 acc[2] = {{0.f,0.f,0.f,0.f},{0.f,0.f,0.f,0.f}};
            // x part: prefetched registers -> hi/lo
            #pragma unroll
            for (int kt = 0; kt < 2; ++kt) {
                const float* v = kt ? xv1 : xv0;
                union { unsigned short u[8]; short8 s; } ah, al;
                #pragma unroll
                for (int e = 0; e < 8; ++e) {
                    unsigned short h = f2bf(v[e]);
                    ah.u[e] = h; al.u[e] = f2bf(v[e] - bf2f(h));
                }
                short8 bh = *(const short8*)&sW0h[(kt * 64 + l) * 8];
                short8 bl = *(const short8*)&sW0l[(kt * 64 + l) * 8];
                MFMA3(acc[kt & 1], ah.s, al.s, bh, bl);
            }
            #pragma unroll
            for (int kt = 0; kt < 16; ++kt) {
                const size_t o = (((size_t)bt * 16 + kt) * 64 + l) * 8;
                short8 ah = *(const short8*)&h0c_h[o];
                short8 al = *(const short8*)&h0c_l[o];
                short8 bh = *(const short8*)&sW0h[((kt + 2) * 64 + l) * 8];
                short8 bl = *(const short8*)&sW0l[((kt + 2) * 64 + l) * 8];
                MFMA3(acc[kt & 1], ah, al, bh, bl);
            }
            #pragma unroll
            for (int q = 0; q < 4; ++q)
                sG[(16 * w + (l >> 4) * 4 + q) * 17 + (l & 15)] = acc[0][q] + acc[1][q];
            __syncthreads();
            {
                const float gi_ = sG[b_local * 17 + jj]      + bias0[0];
                const float gf_ = sG[b_local * 17 + 4 + jj]  + bias0[1];
                const float gg_ = sG[b_local * 17 + 8 + jj]  + bias0[2];
                const float go_ = sG[b_local * 17 + 12 + jj] + bias0[3];
                const float iG = 1.f / (1.f + expf(-gi_));
                const float fG = 1.f / (1.f + expf(-gf_));
                const float gT = tanhf(gg_);
                const float oG = 1.f / (1.f + expf(-go_));
                c0 = fmaf(fG, c0, iG * gT);
                const float h = oG * tanhf(c0);
                const unsigned short hh = f2bf(h);
                const unsigned short hl = f2bf(h - bf2f(hh));
                store_h_pair(h0n_h, hoff, hh, l);
                store_h_pair(h0n_l, hoff, hl, l);
            }
            __syncthreads();
        }

        // prefetch x for it+1 (independent; hides under layer-1 compute)
        if (it + 1 < TT) {
            const float* s0 = x + ((size_t)xrow * TT + (it + 1)) * DIN + ks;
            *(float4*)&xv0[0] = *(const float4*)s0;
            *(float4*)&xv0[4] = *(const float4*)(s0 + 4);
            *(float4*)&xv1[0] = *(const float4*)(s0 + 32);
            *(float4*)&xv1[4] = *(const float4*)(s0 + 36);
        }

        // ================= layer 1, t = it-1 =================
        if (it > 0) {
            f32x4 acc[2] = {{0.f,0.f,0.f,0.f},{0.f,0.f,0.f,0.f}};
            #pragma unroll
            for (int kt = 0; kt < 16; ++kt) {
                const size_t o = (((size_t)bt * 16 + kt) * 64 + l) * 8;
                short8 ah = *(const short8*)&h0c_h[o];
                short8 al = *(const short8*)&h0c_l[o];
                short8 bh = *(const short8*)&sW1h[(kt * 64 + l) * 8];
                short8 bl = *(const short8*)&sW1l[(kt * 64 + l) * 8];
                MFMA3(acc[kt & 1], ah, al, bh, bl);
            }
            #pragma unroll
            for (int kt = 0; kt < 16; ++kt) {
                const size_t o = (((size_t)bt * 16 + kt) * 64 + l) * 8;
                short8 ah = *(const short8*)&h1c_h[o];
                short8 al = *(const short8*)&h1c_l[o];
                short8 bh = *(const short8*)&sW1h[((kt + 16) * 64 + l) * 8];
                short8 bl = *(const short8*)&sW1l[((kt + 16) * 64 + l) * 8];
                MFMA3(acc[kt & 1], ah, al, bh, bl);
            }
            #pragma unroll
            for (int q = 0; q < 4; ++q)
                sG[(16 * w + (l >> 4) * 4 + q) * 17 + (l & 15)] = acc[0][q] + acc[1][q];
            __syncthreads();
            {
                const float gi_ = sG[b_local * 17 + jj]      + bias1[0];
                const float gf_ = sG[b_local * 17 + 4 + jj]  + bias1[1];
                const float gg_ = sG[b_local * 17 + 8 + jj]  + bias1[2];
                const float go_ = sG[b_local * 17 + 12 + jj] + bias1[3];
                const float iG = 1.f / (1.f + expf(-gi_));
                const float fG = 1.f / (1.f + expf(-gf_));
                const float gT = tanhf(gg_);
                const float oG = 1.f / (1.f + expf(-go_));
                c1 = fmaf(fG, c1, iG * gT);
                const float h = oG * tanhf(c1);
                const unsigned short hh = f2bf(h);
                const unsigned short hl = f2bf(h - bf2f(hh));
                store_h_pair(h1n_h, hoff, hh, l);
                store_h_pair(h1n_l, hoff, hl, l);
            }
            __syncthreads();
        }

        group_barrier(gflags, it, jb);
        cur0 ^= 1; cur1 ^= 1;
    }

    // ================= head: out[b] = h1_last . w + b =================
    if (jb == 0) {
        const unsigned short* h1h = ws + (size_t)(4 + cur1 * 2) * HBUF;
        const unsigned short* h1l = h1h + HBUF;
        const int bl_ = tid >> 2;
        const int qd  = tid & 3;
        const int b   = g * BATCH_G + bl_;
        const int btw = b >> 4;
        float s = 0.f;
        #pragma unroll
        for (int jt = qd * 4; jt < qd * 4 + 4; ++jt) {
            #pragma unroll
            for (int q2 = 0; q2 < 4; ++q2) {
                const size_t off = (((size_t)btw * 16 + jt) * 64 + ((b & 15) | (q2 << 4))) * 8;
                short8 vh = *(const short8*)&h1h[off];
                short8 vl = *(const short8*)&h1l[off];
                const int j0 = jt * 32 + q2 * 8;
                #pragma unroll
                for (int e = 0; e < 8; ++e)
                    s += (bf2f((unsigned short)vh[e]) + bf2f((unsigned short)vl[e])) * headw[j0 + e];
            }
        }
        s += __shfl_down(s, 2, 4);
        s += __shfl_down(s, 1, 4);
        if (qd == 0) out[b] = s + headb[0];
    }
}

extern "C" void kernel_launch(void* const* d_in, const int* in_sizes, int n_in,
                              void* d_out, int out_size, void* d_ws, size_t ws_size,
                              hipStream_t stream) {
    const float* x      = (const float*)d_in[0];
    const float* W_ih0  = (const float*)d_in[1];
    const float* W_hh0  = (const float*)d_in[2];
    const float* b_ih0  = (const float*)d_in[3];
    const float* b_hh0  = (const float*)d_in[4];
    const float* W_ih1  = (const float*)d_in[5];
    const float* W_hh1  = (const float*)d_in[6];
    const float* b_ih1  = (const float*)d_in[7];
    const float* b_hh1  = (const float*)d_in[8];
    const float* head_w = (const float*)d_in[9];
    const float* head_b = (const float*)d_in[10];
    float* out = (float*)d_out;
    unsigned short* ws16 = (unsigned short*)d_ws;
    int* flags = (int*)(ws16 + (size_t)8 * HBUF);   // after the 8 h buffers

    // zero h-state (8 buffers) + all iteration flags (fresh every call)
    const size_t zero_bytes = (size_t)8 * HBUF * 2 + (size_t)2 * (TT + 1) * JB_PER_G * 4;
    hipMemsetAsync(d_ws, 0, zero_bytes, stream);

    hipFuncSetAttribute((const void*)lstm_persistent,
                        hipFuncAttributeMaxDynamicSharedMemorySize, LDS_BYTES);
    lstm_persistent<<<dim3(256), dim3(512), LDS_BYTES, stream>>>(
        x, W_ih0, W_hh0, b_ih0, b_hh0, W_ih1, W_hh1, b_ih1, b_hh1,
        head_w, head_b, ws16, flags, out);
}

// Round 7
// 3122.304 us; speedup vs baseline: 1.9658x; 1.4296x over previous
//
#include <hip/hip_runtime.h>

#define HID 512
#define NB  256
#define TT  256
#define DIN 64
#define BATCH_G 128      // batch rows per group
#define JB_PER_G 128     // j-blocks per group
#define HBUF 131072      // shorts per h half-buffer: [16 bt][16 jt][64][8]
#define SLOT_SH (2 * HBUF)            // hi+lo slot, shorts
#define NSLOT 8                       // rotation depth; fence every NSLOT iters

typedef __attribute__((ext_vector_type(8))) short short8;
typedef __attribute__((ext_vector_type(4))) float f32x4;

__device__ __forceinline__ unsigned short f2bf(float f) {
    unsigned int u = __float_as_uint(f);
    u += 0x7FFF + ((u >> 16) & 1);
    return (unsigned short)(u >> 16);
}
__device__ __forceinline__ float bf2f(unsigned short h) {
    return __uint_as_float(((unsigned int)h) << 16);
}

// ---- LLC-coherent (cross-XCD) 4B access, explicit sc0/sc1 cache bits ----
__device__ __forceinline__ void st_u32_llc(unsigned int* p, unsigned int v) {
    asm volatile("global_store_dword %0, %1, off sc0 sc1" :: "v"(p), "v"(v) : "memory");
}
__device__ __forceinline__ unsigned int ld_u32_llc(const unsigned int* p) {
    unsigned int v;
    asm volatile("global_load_dword %0, %1, off sc0 sc1\n\ts_waitcnt vmcnt(0)"
                 : "=v"(v) : "v"(p) : "memory");
    return v;
}

#define MFMA3(acc, ah, al, bh, bl)                                          \
    acc = __builtin_amdgcn_mfma_f32_16x16x32_bf16(ah, bh, acc, 0, 0, 0);    \
    acc = __builtin_amdgcn_mfma_f32_16x16x32_bf16(ah, bl, acc, 0, 0, 0);    \
    acc = __builtin_amdgcn_mfma_f32_16x16x32_bf16(al, bh, acc, 0, 0, 0);

// LDS layout (shorts): sW0 h/l: 18*512 each; sW1 h/l: 32*512 each; then sG floats
#define SW0_N 9216
#define SW1_N 16384
#define LDS_BYTES ((SW0_N * 2 + SW1_N * 2) * 2 + 128 * 17 * 4)

// ---- barrier: vmcnt drain -> LLC flag store -> LLC poll; window fence (1/NSLOT
// ---- iters) runs in a NON-polling wave concurrent with the poll.
__device__ __forceinline__ void group_barrier(int* gflags, int it, int jb, bool fence) {
    asm volatile("s_waitcnt vmcnt(0)" ::: "memory");  // h stores complete at LLC
    __syncthreads();
    unsigned int* slice = (unsigned int*)(gflags + it * JB_PER_G);
    if (threadIdx.x == 0) st_u32_llc(slice + jb, 1u);
    if (fence && threadIdx.x >= 448)                  // wave 7: L1+L2 invalidate
        __builtin_amdgcn_fence(__ATOMIC_ACQUIRE, "agent");
    if (threadIdx.x < JB_PER_G) {                     // waves 0-1 poll (LLC, no L2 fill)
        unsigned int* p = slice + threadIdx.x;
        while (ld_u32_llc(p) == 0u) __builtin_amdgcn_s_sleep(2);
    }
    __syncthreads();
}

// packed 2-lane h store: lanes (l, l+1) hold adjacent j; even lane stores u32
__device__ __forceinline__ void store_h_pair(unsigned short* buf, size_t hoff,
                                             unsigned short v, int l) {
    unsigned int hv = (unsigned int)v;
    unsigned int up = __shfl_down(hv, 1);
    if ((l & 1) == 0)
        st_u32_llc((unsigned int*)(buf + hoff), hv | (up << 16));
}

__global__ __launch_bounds__(512, 2) void lstm_persistent(
    const float* __restrict__ x,
    const float* __restrict__ Wih0, const float* __restrict__ Whh0,
    const float* __restrict__ bih0, const float* __restrict__ bhh0,
    const float* __restrict__ Wih1, const float* __restrict__ Whh1,
    const float* __restrict__ bih1, const float* __restrict__ bhh1,
    const float* __restrict__ headw, const float* __restrict__ headb,
    unsigned short* h0base, unsigned short* h1base,
    int* flags, float* __restrict__ out)
{
    extern __shared__ unsigned short lds[];
    unsigned short* sW0h = lds;
    unsigned short* sW0l = sW0h + SW0_N;
    unsigned short* sW1h = sW0l + SW0_N;
    unsigned short* sW1l = sW1h + SW1_N;
    float* sG = (float*)(sW1l + SW1_N);          // [128][17]

    const int tid = threadIdx.x;
    const int l   = tid & 63;
    const int w   = tid >> 6;         // wave 0..7
    const int bid = blockIdx.x;
    const int g   = bid & 1;          // batch group
    const int jb  = bid >> 1;         // j-block 0..127 (hidden units jb*4..jb*4+3)

    int* gflags = flags + g * (TT + 1) * JB_PER_G;

    // ---------------- weight preload: fp32 -> hi/lo bf16 fragments in LDS ----------------
    const int r  = l & 15;                       // gate-row within tile
    const int ks = (l >> 4) * 8;                 // k-sub offset within 32-chunk
    const int n  = (r >> 2) * HID + jb * 4 + (r & 3);   // weight row index

    {
        for (int kt = w; kt < 18; kt += 8) {
            const float* src = (kt < 2) ? (Wih0 + (size_t)n * DIN + kt * 32 + ks)
                                        : (Whh0 + (size_t)n * HID + (kt - 2) * 32 + ks);
            float v[8];
            *(float4*)&v[0] = *(const float4*)src;
            *(float4*)&v[4] = *(const float4*)(src + 4);
            union { unsigned short u[8]; uint4 q; } ph, pl;
            #pragma unroll
            for (int e = 0; e < 8; ++e) {
                unsigned short h = f2bf(v[e]);
                ph.u[e] = h; pl.u[e] = f2bf(v[e] - bf2f(h));
            }
            *(uint4*)&sW0h[(kt * 64 + l) * 8] = ph.q;
            *(uint4*)&sW0l[(kt * 64 + l) * 8] = pl.q;
        }
        for (int kt = w; kt < 32; kt += 8) {
            const float* src = (kt < 16) ? (Wih1 + (size_t)n * HID + kt * 32 + ks)
                                         : (Whh1 + (size_t)n * HID + (kt - 16) * 32 + ks);
            float v[8];
            *(float4*)&v[0] = *(const float4*)src;
            *(float4*)&v[4] = *(const float4*)(src + 4);
            union { unsigned short u[8]; uint4 q; } ph, pl;
            #pragma unroll
            for (int e = 0; e < 8; ++e) {
                unsigned short h = f2bf(v[e]);
                ph.u[e] = h; pl.u[e] = f2bf(v[e] - bf2f(h));
            }
            *(uint4*)&sW1h[(kt * 64 + l) * 8] = ph.q;
            *(uint4*)&sW1l[(kt * 64 + l) * 8] = pl.q;
        }
    }

    float bias0[4], bias1[4];
    #pragma unroll
    for (int gi = 0; gi < 4; ++gi) {
        const int nn = gi * HID + jb * 4 + (l & 3);
        bias0[gi] = bih0[nn] + bhh0[nn];
        bias1[gi] = bih1[nn] + bhh1[nn];
    }
    float c0 = 0.f, c1 = 0.f;

    const int jj      = l & 3;
    const int b_local = 16 * w + (l >> 2);
    const int b_glob  = g * BATCH_G + b_local;
    const int j_glob  = jb * 4 + jj;
    const size_t hoff = ((((size_t)(b_glob >> 4)) * 16 + (j_glob >> 5)) * 64
                         + ((b_glob & 15) | (((j_glob >> 3) & 3) << 4))) * 8 + (j_glob & 7);

    const int bt = g * 8 + w;        // this wave's global batch tile

    // x prefetch registers
    const int xrow = g * BATCH_G + w * 16 + (l & 15);
    float xv0[8], xv1[8];
    {
        const float* s0 = x + ((size_t)xrow * TT + 0) * DIN + ks;
        *(float4*)&xv0[0] = *(const float4*)s0;
        *(float4*)&xv0[4] = *(const float4*)(s0 + 4);
        *(float4*)&xv1[0] = *(const float4*)(s0 + 32);
        *(float4*)&xv1[4] = *(const float4*)(s0 + 36);
    }

    __syncthreads();                 // weights ready

    for (int it = 0; it <= TT; ++it) {
        // slot map: h0[t] -> slot t&7 ; h1[t] -> slot t&7
        const unsigned short* h0c_h = h0base + (size_t)((it + 7) & 7) * SLOT_SH;
        const unsigned short* h0c_l = h0c_h + HBUF;
        unsigned short* h0n_h = h0base + (size_t)(it & 7) * SLOT_SH;
        unsigned short* h0n_l = h0n_h + HBUF;
        const unsigned short* h1c_h = h1base + (size_t)((it + 6) & 7) * SLOT_SH;
        const unsigned short* h1c_l = h1c_h + HBUF;
        unsigned short* h1n_h = h1base + (size_t)((it + 7) & 7) * SLOT_SH;
        unsigned short* h1n_l = h1n_h + HBUF;

        // ---- hoisted h0 A-fragments: loaded ONCE, used by layer0 AND layer1 ----
        short8 fAh[16], fAl[16];
        #pragma unroll
        for (int kt = 0; kt < 16; ++kt) {
            const size_t o = (((size_t)bt * 16 + kt) * 64 + l) * 8;
            fAh[kt] = *(const short8*)&h0c_h[o];
            fAl[kt] = *(const short8*)&h0c_l[o];
        }

        // ================= layer 0, t = it =================
        if (it < TT) {
            f32x4 acc[2] = {{0.f,0.f,0.f,0.f},{0.f,0.f,0.f,0.f}};
            #pragma unroll
            for (int kt = 0; kt < 2; ++kt) {
                const float* v = kt ? xv1 : xv0;
                union { unsigned short u[8]; short8 s; } ah, al;
                #pragma unroll
                for (int e = 0; e < 8; ++e) {
                    unsigned short h = f2bf(v[e]);
                    ah.u[e] = h; al.u[e] = f2bf(v[e] - bf2f(h));
                }
                short8 bh = *(const short8*)&sW0h[(kt * 64 + l) * 8];
                short8 bl = *(const short8*)&sW0l[(kt * 64 + l) * 8];
                MFMA3(acc[kt & 1], ah.s, al.s, bh, bl);
            }
            #pragma unroll
            for (int kt = 0; kt < 16; ++kt) {
                short8 bh = *(const short8*)&sW0h[((kt + 2) * 64 + l) * 8];
                short8 bl = *(const short8*)&sW0l[((kt + 2) * 64 + l) * 8];
                MFMA3(acc[kt & 1], fAh[kt], fAl[kt], bh, bl);
            }
            #pragma unroll
            for (int q = 0; q < 4; ++q)
                sG[(16 * w + (l >> 4) * 4 + q) * 17 + (l & 15)] = acc[0][q] + acc[1][q];
            __syncthreads();
            {
                const float gi_ = sG[b_local * 17 + jj]      + bias0[0];
                const float gf_ = sG[b_local * 17 + 4 + jj]  + bias0[1];
                const float gg_ = sG[b_local * 17 + 8 + jj]  + bias0[2];
                const float go_ = sG[b_local * 17 + 12 + jj] + bias0[3];
                const float iG = 1.f / (1.f + expf(-gi_));
                const float fG = 1.f / (1.f + expf(-gf_));
                const float gT = tanhf(gg_);
                const float oG = 1.f / (1.f + expf(-go_));
                c0 = fmaf(fG, c0, iG * gT);
                const float h = oG * tanhf(c0);
                const unsigned short hh = f2bf(h);
                const unsigned short hl = f2bf(h - bf2f(hh));
                store_h_pair(h0n_h, hoff, hh, l);
                store_h_pair(h0n_l, hoff, hl, l);
            }
            __syncthreads();
        }

        // prefetch x for it+1 (read-only data: immune to fences)
        if (it + 1 < TT) {
            const float* s0 = x + ((size_t)xrow * TT + (it + 1)) * DIN + ks;
            *(float4*)&xv0[0] = *(const float4*)s0;
            *(float4*)&xv0[4] = *(const float4*)(s0 + 4);
            *(float4*)&xv1[0] = *(const float4*)(s0 + 32);
            *(float4*)&xv1[4] = *(const float4*)(s0 + 36);
        }

        // ================= layer 1, t = it-1 =================
        if (it > 0) {
            f32x4 acc[2] = {{0.f,0.f,0.f,0.f},{0.f,0.f,0.f,0.f}};
            // ys0 part: REUSE carried fragments (no global re-read)
            #pragma unroll
            for (int kt = 0; kt < 16; ++kt) {
                short8 bh = *(const short8*)&sW1h[(kt * 64 + l) * 8];
                short8 bl = *(const short8*)&sW1l[(kt * 64 + l) * 8];
                MFMA3(acc[kt & 1], fAh[kt], fAl[kt], bh, bl);
            }
            #pragma unroll
            for (int kt = 0; kt < 16; ++kt) {
                const size_t o = (((size_t)bt * 16 + kt) * 64 + l) * 8;
                short8 ah = *(const short8*)&h1c_h[o];
                short8 al = *(const short8*)&h1c_l[o];
                short8 bh = *(const short8*)&sW1h[((kt + 16) * 64 + l) * 8];
                short8 bl = *(const short8*)&sW1l[((kt + 16) * 64 + l) * 8];
                MFMA3(acc[kt & 1], ah, al, bh, bl);
            }
            #pragma unroll
            for (int q = 0; q < 4; ++q)
                sG[(16 * w + (l >> 4) * 4 + q) * 17 + (l & 15)] = acc[0][q] + acc[1][q];
            __syncthreads();
            {
                const float gi_ = sG[b_local * 17 + jj]      + bias1[0];
                const float gf_ = sG[b_local * 17 + 4 + jj]  + bias1[1];
                const float gg_ = sG[b_local * 17 + 8 + jj]  + bias1[2];
                const float go_ = sG[b_local * 17 + 12 + jj] + bias1[3];
                const float iG = 1.f / (1.f + expf(-gi_));
                const float fG = 1.f / (1.f + expf(-gf_));
                const float gT = tanhf(gg_);
                const float oG = 1.f / (1.f + expf(-go_));
                c1 = fmaf(fG, c1, iG * gT);
                const float h = oG * tanhf(c1);
                const unsigned short hh = f2bf(h);
                const unsigned short hl = f2bf(h - bf2f(hh));
                store_h_pair(h1n_h, hoff, hh, l);
                store_h_pair(h1n_l, hoff, hl, l);
            }
            __syncthreads();
        }

        group_barrier(gflags, it, jb, (it & 7) == 7);
    }

    // ================= head: out[b] = h1_last . w + b =================
    // h1[t=TT-1] lives in slot (TT-1)&7 = 7; last cached reads of that slot were
    // at it=249, invalidated by the it=255 window fence -> fresh LLC pull here.
    if (jb == 0) {
        const unsigned short* h1h = h1base + (size_t)((TT + 7) & 7) * SLOT_SH;
        const unsigned short* h1l = h1h + HBUF;
        const int bl_ = tid >> 2;
        const int qd  = tid & 3;
        const int b   = g * BATCH_G + bl_;
        const int btw = b >> 4;
        float s = 0.f;
        #pragma unroll
        for (int jt = qd * 4; jt < qd * 4 + 4; ++jt) {
            #pragma unroll
            for (int q2 = 0; q2 < 4; ++q2) {
                const size_t off = (((size_t)btw * 16 + jt) * 64 + ((b & 15) | (q2 << 4))) * 8;
                short8 vh = *(const short8*)&h1h[off];
                short8 vl = *(const short8*)&h1l[off];
                const int j0 = jt * 32 + q2 * 8;
                #pragma unroll
                for (int e = 0; e < 8; ++e)
                    s += (bf2f((unsigned short)vh[e]) + bf2f((unsigned short)vl[e])) * headw[j0 + e];
            }
        }
        s += __shfl_down(s, 2, 4);
        s += __shfl_down(s, 1, 4);
        if (qd == 0) out[b] = s + headb[0];
    }
}

extern "C" void kernel_launch(void* const* d_in, const int* in_sizes, int n_in,
                              void* d_out, int out_size, void* d_ws, size_t ws_size,
                              hipStream_t stream) {
    const float* x      = (const float*)d_in[0];
    const float* W_ih0  = (const float*)d_in[1];
    const float* W_hh0  = (const float*)d_in[2];
    const float* b_ih0  = (const float*)d_in[3];
    const float* b_hh0  = (const float*)d_in[4];
    const float* W_ih1  = (const float*)d_in[5];
    const float* W_hh1  = (const float*)d_in[6];
    const float* b_ih1  = (const float*)d_in[7];
    const float* b_hh1  = (const float*)d_in[8];
    const float* head_w = (const float*)d_in[9];
    const float* head_b = (const float*)d_in[10];
    float* out = (float*)d_out;

    // ws layout: [flags 263KB][pad to 1MB][h0: 8 slots x 512KB][h1: 8 slots x 512KB]
    const size_t SLOT_BYTES = (size_t)SLOT_SH * 2;          // 512 KB
    int* flags = (int*)d_ws;
    unsigned short* h0base = (unsigned short*)((char*)d_ws + (1 << 20));
    unsigned short* h1base = (unsigned short*)((char*)d_ws + (1 << 20) + NSLOT * SLOT_BYTES);

    // zero: all flags + the t=-1 slots (slot 7 of each chain)
    hipMemsetAsync(d_ws, 0, (size_t)2 * (TT + 1) * JB_PER_G * 4, stream);
    hipMemsetAsync((char*)h0base + 7 * SLOT_BYTES, 0, SLOT_BYTES, stream);
    hipMemsetAsync((char*)h1base + 7 * SLOT_BYTES, 0, SLOT_BYTES, stream);

    hipFuncSetAttribute((const void*)lstm_persistent,
                        hipFuncAttributeMaxDynamicSharedMemorySize, LDS_BYTES);
    lstm_persistent<<<dim3(256), dim3(512), LDS_BYTES, stream>>>(
        x, W_ih0, W_hh0, b_ih0, b_hh0, W_ih1, W_hh1, b_ih1, b_hh1,
        head_w, head_b, h0base, h1base, flags, out);
}